// Round 8
// baseline (306.702 us; speedup 1.0000x reference)
//
#include <hip/hip_runtime.h>
#include <hip/hip_bf16.h>
#include <hip/hip_cooperative_groups.h>

namespace cg = cooperative_groups;

// Problem constants
#define B_    16
#define T_    2048
#define H_    512
#define BT_   32768      // B*T tokens
#define DIN   80         // obs 64 + act 16
#define DPAD  128        // padded K for embed GEMM (2 x 64)
#define L_    64         // scan chunk length
#define C_    32         // chunks per batch (T/L)
#define O_    64         // output dim
#define NCHUNK (BT_ / L_)  // 512 total chunks

typedef __attribute__((ext_vector_type(8))) short short8;
typedef __attribute__((ext_vector_type(4))) float f32x4;
typedef __attribute__((ext_vector_type(4))) float float4v;

__device__ __forceinline__ float bf2f(unsigned short u) {
  union { unsigned int i; float f; } x; x.i = ((unsigned int)u) << 16; return x.f;
}
__device__ __forceinline__ unsigned short f2bf(float f) {
  union { float f; unsigned int i; } x; x.f = f;
  unsigned int r = x.i + 0x7fffu + ((x.i >> 16) & 1u);
  return (unsigned short)(r >> 16);
}

#define WE_N  (H_ * DPAD)            // 65536
#define WB_N  (H_ * H_)              // 262144
#define WO_N  (O_ * H_)              // 32768
#define PW_N  (WE_N + WB_N + WO_N + H_)   // 360960

// ---------------------------------------------------------------------------
// Cooperative mega-kernel: prep -> embed -> bproj -> carry+scan+out.
// 256 blocks x 512 threads, 1 block/CU (128KB LDS), grid.sync() between
// phases (device-scope __threadfence before each sync handles cross-XCD e).
// Block mapping (all phases): X = bid&7 (XCD chunk), mt = X*16 + (j>>1),
// nt = j&1 -> all producers/consumers of a block's data live on one XCD.
// ---------------------------------------------------------------------------
__global__ __launch_bounds__(512) void ssm_mega(
    const float* __restrict__ obs, const float* __restrict__ act,
    const float* __restrict__ W_e, const float* __restrict__ b_e,
    const float* __restrict__ a_raw, const float* __restrict__ W_B,
    const float* __restrict__ W_out, const float* __restrict__ b_out,
    unsigned short* __restrict__ Web, unsigned short* __restrict__ WBb,
    unsigned short* __restrict__ Woutb, float* __restrict__ aarr,
    float* __restrict__ powa, unsigned short* __restrict__ u,
    unsigned short* __restrict__ v, float* __restrict__ e,
    float* __restrict__ y)
{
  cg::grid_group grid = cg::this_grid();
  __shared__ __align__(16) unsigned char lds[131072];

  const int tid  = threadIdx.x;
  const int lane = tid & 63;
  const int wid  = tid >> 6;
  const int wr   = wid >> 2;          // 0..1  (M)
  const int wc   = wid & 3;           // 0..3  (N)
  const int cl   = lane & 15;
  const int kgrp = lane >> 4;         // 0..3
  const int rg   = kgrp * 4;

  const int X  = (int)blockIdx.x & 7;
  const int j  = (int)blockIdx.x >> 3;
  const int mt = X * 16 + (j >> 1);
  const int nt = j & 1;
  const int row0 = mt * 256, col0 = nt * 256;

  // ========== Phase P: weight prep ==========
  {
    for (int idx = (int)blockIdx.x * 512 + tid; idx < PW_N; idx += 256 * 512) {
      if (idx < WE_N) {
        const int h = idx >> 7, d = idx & 127;
        Web[idx] = f2bf(d < DIN ? W_e[h * DIN + d] : 0.f);
      } else if (idx < WE_N + WB_N) {
        const int j2 = idx - WE_N;
        WBb[j2] = f2bf(W_B[j2]);
      } else if (idx < WE_N + WB_N + WO_N) {
        const int j2 = idx - (WE_N + WB_N);
        Woutb[j2] = f2bf(W_out[j2]);
      } else {
        const int h = idx - (WE_N + WB_N + WO_N);
        const float a = tanhf(a_raw[h]);
        aarr[h] = a;
        float p = a;
        #pragma unroll
        for (int i = 0; i < 16; ++i) { powa[i * H_ + h] = p; p *= a; }
      }
    }
  }
  __threadfence();
  grid.sync();

  // ========== Phase E: embed GEMM (inline x conversion, K=128) ==========
  {
    // A-tiles: f32->bf16 reg conversion, swizzled ds_write
    {
      const int row  = tid >> 1;        // 0..255
      const int half = tid & 1;
      {
        const float4v* src = (const float4v*)(obs + (size_t)(row0 + row) * 64 + half * 32);
        float f[32];
        #pragma unroll
        for (int i = 0; i < 8; ++i) {
          const float4v t4 = src[i];
          f[i*4+0]=t4[0]; f[i*4+1]=t4[1]; f[i*4+2]=t4[2]; f[i*4+3]=t4[3];
        }
        #pragma unroll
        for (int cc = 0; cc < 4; ++cc) {
          short8 o8;
          #pragma unroll
          for (int jj = 0; jj < 8; ++jj) o8[jj] = (short)f2bf(f[cc*8+jj]);
          const int c16 = half * 4 + cc;
          *(short8*)(lds + row * 128 + ((c16 ^ (row & 7)) << 4)) = o8;
        }
      }
      {
        short8 z8;
        #pragma unroll
        for (int jj = 0; jj < 8; ++jj) z8[jj] = 0;
        if (half == 0) {
          const float4v* asrc = (const float4v*)(act + (size_t)(row0 + row) * 16);
          float g[16];
          #pragma unroll
          for (int i = 0; i < 4; ++i) {
            const float4v t4 = asrc[i];
            g[i*4+0]=t4[0]; g[i*4+1]=t4[1]; g[i*4+2]=t4[2]; g[i*4+3]=t4[3];
          }
          #pragma unroll
          for (int cc = 0; cc < 2; ++cc) {
            short8 o8;
            #pragma unroll
            for (int jj = 0; jj < 8; ++jj) o8[jj] = (short)f2bf(g[cc*8+jj]);
            *(short8*)(lds + 65536 + row * 128 + ((cc ^ (row & 7)) << 4)) = o8;
          }
          #pragma unroll
          for (int cc = 2; cc < 4; ++cc)
            *(short8*)(lds + 65536 + row * 128 + ((cc ^ (row & 7)) << 4)) = z8;
        } else {
          #pragma unroll
          for (int cc = 4; cc < 8; ++cc)
            *(short8*)(lds + 65536 + row * 128 + ((cc ^ (row & 7)) << 4)) = z8;
        }
      }
    }
    // B-tiles (Web) via global_load_lds
    #pragma unroll
    for (int q = 0; q < 2; ++q) {
      #pragma unroll
      for (int r = 0; r < 4; ++r) {
        const int o   = r * 8192 + tid * 16;
        const int col = o >> 7;
        const int c16 = (o >> 4) & 7;
        const int kk  = (c16 ^ (col & 7)) << 3;
        __builtin_amdgcn_global_load_lds(
            (const __attribute__((address_space(1))) void*)
                (Web + (size_t)(col0 + col) * DPAD + q * 64 + kk),
            (__attribute__((address_space(3))) void*)(lds + q * 65536 + 32768 + o),
            16, 0, 0);
      }
    }
    __syncthreads();

    f32x4 acc[8][4];
    #pragma unroll
    for (int m = 0; m < 8; ++m)
      #pragma unroll
      for (int n = 0; n < 4; ++n) acc[m][n] = f32x4{0.f, 0.f, 0.f, 0.f};

    #pragma unroll
    for (int q = 0; q < 2; ++q) {
      const unsigned char* bufp = lds + q * 65536;
      short8 bfr[4][2];
      #pragma unroll
      for (int n = 0; n < 4; ++n) {
        const int col = wc * 64 + n * 16 + cl;
        #pragma unroll
        for (int ks = 0; ks < 2; ++ks)
          bfr[n][ks] = *(const short8*)(bufp + 32768 + col * 128 +
                                        ((((ks << 2) + kgrp) ^ (col & 7)) << 4));
      }
      #pragma unroll
      for (int g = 0; g < 4; ++g) {
        short8 af[2][2];
        #pragma unroll
        for (int mm = 0; mm < 2; ++mm) {
          const int row = wr * 128 + (g * 2 + mm) * 16 + cl;
          #pragma unroll
          for (int ks = 0; ks < 2; ++ks)
            af[mm][ks] = *(const short8*)(bufp + row * 128 +
                                          ((((ks << 2) + kgrp) ^ (row & 7)) << 4));
        }
        #pragma unroll
        for (int ks = 0; ks < 2; ++ks)
          #pragma unroll
          for (int mm = 0; mm < 2; ++mm)
            #pragma unroll
            for (int n = 0; n < 4; ++n)
              acc[g * 2 + mm][n] = __builtin_amdgcn_mfma_f32_16x16x32_bf16(
                  af[mm][ks], bfr[n][ks], acc[g * 2 + mm][n], 0, 0, 0);
      }
    }
    // Epilogue: relu(acc + b_e) -> u bf16
    #pragma unroll
    for (int m = 0; m < 8; ++m) {
      #pragma unroll
      for (int n = 0; n < 4; ++n) {
        const int gc = col0 + wc * 64 + n * 16 + cl;
        const float be = b_e[gc];
        #pragma unroll
        for (int e2 = 0; e2 < 4; ++e2) {
          const int gr = row0 + wr * 128 + m * 16 + rg + e2;
          u[(size_t)gr * H_ + gc] = f2bf(fmaxf(acc[m][n][e2] + be, 0.f));
        }
      }
    }
  }
  __threadfence();
  grid.sync();

  // ========== Phase G: B-projection (counted-vmcnt pipeline) ==========
  {
    constexpr int NT = 8;
    auto stageA = [&](int q, int buf) {
      const int k0 = q * 64;
      #pragma unroll
      for (int r = 0; r < 4; ++r) {
        const int o   = r * 8192 + tid * 16;
        const int row = o >> 7;
        const int c16 = (o >> 4) & 7;
        const int kk  = (c16 ^ (row & 7)) << 3;
        __builtin_amdgcn_global_load_lds(
            (const __attribute__((address_space(1))) void*)
                (u + (size_t)(row0 + row) * H_ + k0 + kk),
            (__attribute__((address_space(3))) void*)(lds + buf * 65536 + o),
            16, 0, 0);
      }
    };
    auto stageB_round = [&](int q, int buf, int r) {
      const int k0 = q * 64;
      const int o   = r * 8192 + tid * 16;
      const int col = o >> 7;
      const int c16 = (o >> 4) & 7;
      const int kk  = (c16 ^ (col & 7)) << 3;
      __builtin_amdgcn_global_load_lds(
          (const __attribute__((address_space(1))) void*)
              (WBb + (size_t)(col0 + col) * H_ + k0 + kk),
          (__attribute__((address_space(3))) void*)(lds + buf * 65536 + 32768 + o),
          16, 0, 0);
    };

    f32x4 acc[8][4];
    #pragma unroll
    for (int m = 0; m < 8; ++m)
      #pragma unroll
      for (int n = 0; n < 4; ++n) acc[m][n] = f32x4{0.f, 0.f, 0.f, 0.f};

    stageA(0, 0);
    #pragma unroll
    for (int r = 0; r < 4; ++r) stageB_round(0, 0, r);
    #pragma unroll
    for (int r = 0; r < 4; ++r) stageB_round(1, 1, r);
    asm volatile("s_waitcnt vmcnt(4)" ::: "memory");
    __builtin_amdgcn_sched_barrier(0);
    __builtin_amdgcn_s_barrier();

    for (int q = 0; q < NT; ++q) {
      const int cur = q & 1;
      const unsigned char* bufp = lds + cur * 65536;

      if (q + 1 < NT) stageA(q + 1, cur ^ 1);

      short8 bfr[4][2];
      #pragma unroll
      for (int n = 0; n < 4; ++n) {
        const int col = wc * 64 + n * 16 + cl;
        #pragma unroll
        for (int ks = 0; ks < 2; ++ks)
          bfr[n][ks] = *(const short8*)(bufp + 32768 + col * 128 +
                                        ((((ks << 2) + kgrp) ^ (col & 7)) << 4));
      }
      asm volatile("s_waitcnt lgkmcnt(0)" ::: "memory");
      __builtin_amdgcn_sched_barrier(0);
      __builtin_amdgcn_s_barrier();                 // bar1: all B reads done

      __builtin_amdgcn_s_setprio(1);
      #pragma unroll
      for (int g = 0; g < 4; ++g) {
        if (q + 2 < NT) stageB_round(q + 2, cur, g);
        short8 af[2][2];
        #pragma unroll
        for (int mm = 0; mm < 2; ++mm) {
          const int row = wr * 128 + (g * 2 + mm) * 16 + cl;
          #pragma unroll
          for (int ks = 0; ks < 2; ++ks)
            af[mm][ks] = *(const short8*)(bufp + row * 128 +
                                          ((((ks << 2) + kgrp) ^ (row & 7)) << 4));
        }
        #pragma unroll
        for (int ks = 0; ks < 2; ++ks)
          #pragma unroll
          for (int mm = 0; mm < 2; ++mm)
            #pragma unroll
            for (int n = 0; n < 4; ++n)
              acc[g * 2 + mm][n] = __builtin_amdgcn_mfma_f32_16x16x32_bf16(
                  af[mm][ks], bfr[n][ks], acc[g * 2 + mm][n], 0, 0, 0);
      }
      __builtin_amdgcn_s_setprio(0);

      if (q + 2 < NT) {
        asm volatile("s_waitcnt vmcnt(4)" ::: "memory");
      } else if (q + 1 < NT) {
        asm volatile("s_waitcnt vmcnt(0)" ::: "memory");
      }
      __builtin_amdgcn_sched_barrier(0);
      __builtin_amdgcn_s_barrier();                 // bar2
    }

    // Epilogue: v write
    #pragma unroll
    for (int m = 0; m < 8; ++m) {
      #pragma unroll
      for (int n = 0; n < 4; ++n) {
        const int gc = col0 + wc * 64 + n * 16 + cl;
        #pragma unroll
        for (int e2 = 0; e2 < 4; ++e2) {
          const int gr = row0 + wr * 128 + m * 16 + rg + e2;
          v[(size_t)gr * H_ + gc] = f2bf(acc[m][n][e2]);
        }
      }
    }
    // Chunk-end e: wave spans 2 chunks (m 0..3, m 4..7)
    #pragma unroll
    for (int c = 0; c < 2; ++c) {
      const int chunk = ((row0 + wr * 128) >> 6) + c;
      #pragma unroll
      for (int n = 0; n < 4; ++n) {
        const int h = col0 + wc * 64 + n * 16 + cl;
        const float a16 = powa[15 * H_ + h];
        float ep = 0.f;
        #pragma unroll
        for (int e2 = 0; e2 < 4; ++e2) {
          const int k = 15 - rg - e2;
          const float wk = (k == 0) ? 1.f : powa[(size_t)(k - 1) * H_ + h];
          float hsum = acc[c * 4 + 0][n][e2];
          hsum = fmaf(hsum, a16, acc[c * 4 + 1][n][e2]);
          hsum = fmaf(hsum, a16, acc[c * 4 + 2][n][e2]);
          hsum = fmaf(hsum, a16, acc[c * 4 + 3][n][e2]);
          ep = fmaf(wk, hsum, ep);
        }
        ep += __shfl_xor(ep, 16);
        ep += __shfl_xor(ep, 32);
        if (kgrp == 0)
          e[(size_t)chunk * H_ + h] = ep;
      }
    }
  }
  __threadfence();
  grid.sync();

  // ========== Phase S: inline carry + scan + out-projection ==========
  // Block handles its own 2 chunks: chunk = 4*mt + 2*nt + (tid>>8).
  // Each 256-thread half uses 64KB of LDS.
  {
    const int half  = tid >> 8;          // 0,1
    const int t256  = tid & 255;
    const int chunk = mt * 4 + nt * 2 + half;
    const int b = chunk >> 5, c = chunk & 31;
    const int row_base = chunk * L_;
    unsigned char* sb = lds + half * 65536;

    // carry (batched-8 predicated Horner over predecessors' e)
    {
      const int h0 = t256 * 2;
      const float a0 = aarr[h0], a1 = aarr[h0 + 1];
      float aL0 = a0 * a0, aL1 = a1 * a1;
      aL0 *= aL0; aL1 *= aL1;
      aL0 *= aL0; aL1 *= aL1;
      aL0 *= aL0; aL1 *= aL1;
      aL0 *= aL0; aL1 *= aL1;
      aL0 *= aL0; aL1 *= aL1;                       // a^64
      float s0 = 0.f, s1 = 0.f;
      #pragma unroll
      for (int g = 0; g < 4; ++g) {
        float ev0[8], ev1[8];
        #pragma unroll
        for (int k = 0; k < 8; ++k) {
          const size_t o = ((size_t)(b * C_ + g * 8 + k)) * H_ + h0;
          ev0[k] = e[o]; ev1[k] = e[o + 1];
        }
        #pragma unroll
        for (int k = 0; k < 8; ++k) {
          const bool pred = (g * 8 + k) < c;
          s0 = pred ? fmaf(aL0, s0, ev0[k]) : s0;
          s1 = pred ? fmaf(aL1, s1, ev1[k]) : s1;
        }
      }
      // scan chunk, write bf16 s-tile to XOR-swizzled LDS
      const unsigned int* vp = (const unsigned int*)v + (size_t)row_base * (H_ / 2) + t256;
      #pragma unroll 8
      for (int t = 0; t < L_; ++t) {
        const unsigned int pv = vp[(size_t)t * (H_ / 2)];
        s0 = fmaf(a0, s0, bf2f((unsigned short)(pv & 0xffff)));
        s1 = fmaf(a1, s1, bf2f((unsigned short)(pv >> 16)));
        const int byte = t * 1024 + ((t256 * 4) ^ ((t & 7) << 4));
        *(unsigned int*)(sb + byte) =
            (unsigned int)f2bf(s0) | ((unsigned int)f2bf(s1) << 16);
      }
    }
    __syncthreads();

    // y = s @ Wo^T + b_out
    f32x4 acc[4];
    #pragma unroll
    for (int n = 0; n < 4; ++n) acc[n] = f32x4{0.f, 0.f, 0.f, 0.f};
    const int w2 = t256 >> 6;
    const int r = w2 * 16 + cl;
    const int kof = kgrp * 8;
    #pragma unroll 4
    for (int k0 = 0; k0 < H_; k0 += 32) {
      const int byte = r * 1024 + (((k0 + kof) * 2) ^ ((r & 7) << 4));
      const short8 af = *(const short8*)(sb + byte);
      #pragma unroll
      for (int n = 0; n < 4; ++n) {
        const short8 bf = *(const short8*)(Woutb + (size_t)(n * 16 + cl) * H_ + k0 + kof);
        acc[n] = __builtin_amdgcn_mfma_f32_16x16x32_bf16(af, bf, acc[n], 0, 0, 0);
      }
    }
    #pragma unroll
    for (int n = 0; n < 4; ++n) {
      #pragma unroll
      for (int e2 = 0; e2 < 4; ++e2) {
        const int gr = row_base + w2 * 16 + rg + e2;
        const int gc = n * 16 + cl;
        y[(size_t)gr * O_ + gc] = acc[n][e2] + b_out[gc];
      }
    }
  }
}

// ---------------------------------------------------------------------------
extern "C" void kernel_launch(void* const* d_in, const int* in_sizes, int n_in,
                              void* d_out, int out_size, void* d_ws, size_t ws_size,
                              hipStream_t stream)
{
  const float* obs   = (const float*)d_in[0];
  const float* act   = (const float*)d_in[1];
  const float* W_e   = (const float*)d_in[2];
  const float* b_e   = (const float*)d_in[3];
  const float* a_raw = (const float*)d_in[4];
  const float* W_B   = (const float*)d_in[5];
  const float* W_out = (const float*)d_in[6];
  const float* b_out = (const float*)d_in[7];
  float* y = (float*)d_out;

  char* w = (char*)d_ws;
  auto carve = [&](size_t bytes) {
    char* p = w; w += (bytes + 255) & ~(size_t)255; return p;
  };
  unsigned short* Web   = (unsigned short*)carve((size_t)H_ * DPAD * 2);
  unsigned short* WBb   = (unsigned short*)carve((size_t)H_ * H_ * 2);
  unsigned short* Woutb = (unsigned short*)carve((size_t)O_ * H_ * 2);
  float*          aarr  = (float*)carve((size_t)H_ * 4);
  float*          powa  = (float*)carve((size_t)16 * H_ * 4);
  unsigned short* u     = (unsigned short*)carve((size_t)BT_ * H_ * 2);    // 33.5 MB
  unsigned short* v     = (unsigned short*)carve((size_t)BT_ * H_ * 2);    // 33.5 MB
  float*          e     = (float*)carve((size_t)NCHUNK * H_ * 4);          // 1 MB

  void* args[] = {
    (void*)&obs, (void*)&act, (void*)&W_e, (void*)&b_e, (void*)&a_raw,
    (void*)&W_B, (void*)&W_out, (void*)&b_out,
    (void*)&Web, (void*)&WBb, (void*)&Woutb, (void*)&aarr, (void*)&powa,
    (void*)&u, (void*)&v, (void*)&e, (void*)&y
  };
  hipLaunchCooperativeKernel((void*)ssm_mega, dim3(256), dim3(512),
                             args, 0, stream);
}

// Round 9
// 68.211 us; speedup vs baseline: 4.4963x; 4.4963x over previous
//
#include <hip/hip_runtime.h>
#include <hip/hip_bf16.h>

// Problem constants
#define B_    16
#define T_    2048
#define H_    512
#define BT_   32768      // B*T tokens
#define DIN   80         // obs 64 + act 16
#define L_    64         // scan chunk length
#define C_    32         // chunks per batch (T/L)
#define O_    64         // output dim
#define NCHUNK (BT_ / L_)  // 512 total chunks

typedef __attribute__((ext_vector_type(8))) short short8;
typedef __attribute__((ext_vector_type(4))) float f32x4;
typedef __attribute__((ext_vector_type(4))) float float4v;

__device__ __forceinline__ float bf2f(unsigned short u) {
  union { unsigned int i; float f; } x; x.i = ((unsigned int)u) << 16; return x.f;
}
__device__ __forceinline__ unsigned short f2bf(float f) {
  union { float f; unsigned int i; } x; x.f = f;
  unsigned int r = x.i + 0x7fffu + ((x.i >> 16) & 1u);
  return (unsigned short)(r >> 16);
}

#define WB_N  (H_ * H_)              // 262144
#define WO_N  (O_ * H_)              // 32768

// ---------------------------------------------------------------------------
// Embed GEMM with fully-inline prep (3-kernel plan, kernel 1 of 3):
//  - prologue (strided): WB -> bf16, W_out -> bf16, tanh(a) + power table
//    (consumed only by LATER kernels; kernel boundary provides ordering)
//  - A-tile: concat(obs,act) f32 -> bf16 regs -> swizzled ds_write
//  - B-tile: W_e f32 -> bf16 regs -> swizzled ds_write (no Web buffer)
//  - one __syncthreads, then 2 K-tiles (K=128 padded) of barrier-free MFMA
// 256 blocks x 512 threads = 8 waves (2M x 4N); wave C = 128x64.
// u = relu(x @ We^T + b_e) -> bf16 [BT][512].
// ---------------------------------------------------------------------------
__global__ __launch_bounds__(512) void embed_gemm(
    const float* __restrict__ obs, const float* __restrict__ act,
    const float* __restrict__ W_e, const float* __restrict__ b_e,
    const float* __restrict__ a_raw, const float* __restrict__ W_B,
    const float* __restrict__ W_out,
    unsigned short* __restrict__ WBb, unsigned short* __restrict__ Woutb,
    float* __restrict__ aarr, float* __restrict__ powa,
    unsigned short* __restrict__ u)
{
  __shared__ __align__(16) unsigned char lds[131072];

  const int tid  = threadIdx.x;
  const int lane = tid & 63;
  const int wid  = tid >> 6;
  const int wr   = wid >> 2;
  const int wc   = wid & 3;
  const int cl   = lane & 15;
  const int kgrp = lane >> 4;
  const int rg   = kgrp * 4;

  const int X  = (int)blockIdx.x & 7;
  const int j  = (int)blockIdx.x >> 3;
  const int mt = X * 16 + (j >> 1);
  const int nt = j & 1;
  const int row0 = mt * 256, col0 = nt * 256;

  // ---- Prologue: strided prep of WBb / Woutb / aarr+powa ----
  {
    const int g = (int)blockIdx.x * 512 + tid;   // 0..131071
    // WB: 262144 elems, 2 per thread
    #pragma unroll
    for (int r = 0; r < 2; ++r) {
      const int idx = g * 2 + r;
      WBb[idx] = f2bf(W_B[idx]);
    }
    if (g < WO_N) Woutb[g] = f2bf(W_out[g]);
    if (g < H_) {
      const float a = tanhf(a_raw[g]);
      aarr[g] = a;
      float p = a;
      #pragma unroll
      for (int i = 0; i < 16; ++i) { powa[i * H_ + g] = p; p *= a; }
    }
  }

  // ---- A-tiles: inline f32->bf16, swizzled ds_write (bufq A regions) ----
  {
    const int row  = tid >> 1;        // 0..255 local token
    const int half = tid & 1;
    {
      const float4v* src = (const float4v*)(obs + (size_t)(row0 + row) * 64 + half * 32);
      float f[32];
      #pragma unroll
      for (int i = 0; i < 8; ++i) {
        const float4v t4 = src[i];
        f[i*4+0]=t4[0]; f[i*4+1]=t4[1]; f[i*4+2]=t4[2]; f[i*4+3]=t4[3];
      }
      #pragma unroll
      for (int cc = 0; cc < 4; ++cc) {
        short8 o8;
        #pragma unroll
        for (int jj = 0; jj < 8; ++jj) o8[jj] = (short)f2bf(f[cc*8+jj]);
        const int c16 = half * 4 + cc;
        *(short8*)(lds + row * 128 + ((c16 ^ (row & 7)) << 4)) = o8;
      }
    }
    {
      short8 z8;
      #pragma unroll
      for (int jj = 0; jj < 8; ++jj) z8[jj] = 0;
      if (half == 0) {
        const float4v* asrc = (const float4v*)(act + (size_t)(row0 + row) * 16);
        float g2[16];
        #pragma unroll
        for (int i = 0; i < 4; ++i) {
          const float4v t4 = asrc[i];
          g2[i*4+0]=t4[0]; g2[i*4+1]=t4[1]; g2[i*4+2]=t4[2]; g2[i*4+3]=t4[3];
        }
        #pragma unroll
        for (int cc = 0; cc < 2; ++cc) {
          short8 o8;
          #pragma unroll
          for (int jj = 0; jj < 8; ++jj) o8[jj] = (short)f2bf(g2[cc*8+jj]);
          *(short8*)(lds + 65536 + row * 128 + ((cc ^ (row & 7)) << 4)) = o8;
        }
        #pragma unroll
        for (int cc = 2; cc < 4; ++cc)
          *(short8*)(lds + 65536 + row * 128 + ((cc ^ (row & 7)) << 4)) = z8;
      } else {
        #pragma unroll
        for (int cc = 4; cc < 8; ++cc)
          *(short8*)(lds + 65536 + row * 128 + ((cc ^ (row & 7)) << 4)) = z8;
      }
    }
  }
  // ---- B-tiles: W_e inline f32->bf16, swizzled ds_write (bufq B regions) ----
  {
    const int colL = tid >> 1;        // 0..255 local col
    const int col  = col0 + colL;
    const int half = tid & 1;
    // K-tile 0: W_e[col][half*32 .. +32)
    {
      const float4v* src = (const float4v*)(W_e + (size_t)col * DIN + half * 32);
      float f[32];
      #pragma unroll
      for (int i = 0; i < 8; ++i) {
        const float4v t4 = src[i];
        f[i*4+0]=t4[0]; f[i*4+1]=t4[1]; f[i*4+2]=t4[2]; f[i*4+3]=t4[3];
      }
      #pragma unroll
      for (int cc = 0; cc < 4; ++cc) {
        short8 o8;
        #pragma unroll
        for (int jj = 0; jj < 8; ++jj) o8[jj] = (short)f2bf(f[cc*8+jj]);
        const int c16 = half * 4 + cc;
        *(short8*)(lds + 32768 + colL * 128 + ((c16 ^ (colL & 7)) << 4)) = o8;
      }
    }
    // K-tile 1: W_e[col][64..79] then zero-pad
    {
      short8 z8;
      #pragma unroll
      for (int jj = 0; jj < 8; ++jj) z8[jj] = 0;
      if (half == 0) {
        const float4v* src = (const float4v*)(W_e + (size_t)col * DIN + 64);
        float g2[16];
        #pragma unroll
        for (int i = 0; i < 4; ++i) {
          const float4v t4 = src[i];
          g2[i*4+0]=t4[0]; g2[i*4+1]=t4[1]; g2[i*4+2]=t4[2]; g2[i*4+3]=t4[3];
        }
        #pragma unroll
        for (int cc = 0; cc < 2; ++cc) {
          short8 o8;
          #pragma unroll
          for (int jj = 0; jj < 8; ++jj) o8[jj] = (short)f2bf(g2[cc*8+jj]);
          *(short8*)(lds + 98304 + colL * 128 + ((cc ^ (colL & 7)) << 4)) = o8;
        }
        #pragma unroll
        for (int cc = 2; cc < 4; ++cc)
          *(short8*)(lds + 98304 + colL * 128 + ((cc ^ (colL & 7)) << 4)) = z8;
      } else {
        #pragma unroll
        for (int cc = 4; cc < 8; ++cc)
          *(short8*)(lds + 98304 + colL * 128 + ((cc ^ (colL & 7)) << 4)) = z8;
      }
    }
  }
  __syncthreads();

  f32x4 acc[8][4];
  #pragma unroll
  for (int m = 0; m < 8; ++m)
    #pragma unroll
    for (int n = 0; n < 4; ++n) acc[m][n] = f32x4{0.f, 0.f, 0.f, 0.f};

  #pragma unroll
  for (int q = 0; q < 2; ++q) {
    const unsigned char* bufp = lds + q * 65536;
    short8 bfr[4][2];
    #pragma unroll
    for (int n = 0; n < 4; ++n) {
      const int col = wc * 64 + n * 16 + cl;
      #pragma unroll
      for (int ks = 0; ks < 2; ++ks)
        bfr[n][ks] = *(const short8*)(bufp + 32768 + col * 128 +
                                      ((((ks << 2) + kgrp) ^ (col & 7)) << 4));
    }
    #pragma unroll
    for (int g = 0; g < 4; ++g) {
      short8 af[2][2];
      #pragma unroll
      for (int mm = 0; mm < 2; ++mm) {
        const int row = wr * 128 + (g * 2 + mm) * 16 + cl;
        #pragma unroll
        for (int ks = 0; ks < 2; ++ks)
          af[mm][ks] = *(const short8*)(bufp + row * 128 +
                                        ((((ks << 2) + kgrp) ^ (row & 7)) << 4));
      }
      #pragma unroll
      for (int ks = 0; ks < 2; ++ks)
        #pragma unroll
        for (int mm = 0; mm < 2; ++mm)
          #pragma unroll
          for (int n = 0; n < 4; ++n)
            acc[g * 2 + mm][n] = __builtin_amdgcn_mfma_f32_16x16x32_bf16(
                af[mm][ks], bfr[n][ks], acc[g * 2 + mm][n], 0, 0, 0);
    }
  }

  // Epilogue: relu(acc + b_e) -> u bf16
  #pragma unroll
  for (int m = 0; m < 8; ++m) {
    #pragma unroll
    for (int n = 0; n < 4; ++n) {
      const int gc = col0 + wc * 64 + n * 16 + cl;
      const float be = b_e[gc];
      #pragma unroll
      for (int e2 = 0; e2 < 4; ++e2) {
        const int gr = row0 + wr * 128 + m * 16 + rg + e2;
        u[(size_t)gr * H_ + gc] = f2bf(fmaxf(acc[m][n][e2] + be, 0.f));
      }
    }
  }
}

// ---------------------------------------------------------------------------
// B-projection GEMM (kernel 2 of 3): v = u @ WB^T, 256x256 tiles, K-tiles of
// 64, counted-vmcnt pipeline (T4), LDS XOR-swizzle (T2), XCD mapping (T1),
// setprio around MFMA (T5), stageB interleaved between MFMA g-groups.
// CE epilogue: chunk-end sums e[chunk][h].
// ---------------------------------------------------------------------------
__global__ __launch_bounds__(512) void gemm_bproj(
    const unsigned short* __restrict__ A, const unsigned short* __restrict__ Bt,
    unsigned short* __restrict__ Cb,
    const float* __restrict__ powa, float* __restrict__ e)
{
  constexpr int NT = 8;
  __shared__ __align__(16) unsigned char lds[131072];

  const int tid  = threadIdx.x;
  const int lane = tid & 63;
  const int wid  = tid >> 6;
  const int wr   = wid >> 2;
  const int wc   = wid & 3;
  const int cl   = lane & 15;
  const int kgrp = lane >> 4;
  const int rg   = kgrp * 4;

  const int X  = (int)blockIdx.x & 7;
  const int j  = (int)blockIdx.x >> 3;
  const int mt = X * 16 + (j >> 1);
  const int nt = j & 1;
  const int row0 = mt * 256, col0 = nt * 256;

  auto stageA = [&](int q, int buf) {
    const int k0 = q * 64;
    #pragma unroll
    for (int r = 0; r < 4; ++r) {
      const int o   = r * 8192 + tid * 16;
      const int row = o >> 7;
      const int c16 = (o >> 4) & 7;
      const int kk  = (c16 ^ (row & 7)) << 3;
      __builtin_amdgcn_global_load_lds(
          (const __attribute__((address_space(1))) void*)
              (A + (size_t)(row0 + row) * H_ + k0 + kk),
          (__attribute__((address_space(3))) void*)(lds + buf * 65536 + o),
          16, 0, 0);
    }
  };
  auto stageB_round = [&](int q, int buf, int r) {
    const int k0 = q * 64;
    const int o   = r * 8192 + tid * 16;
    const int col = o >> 7;
    const int c16 = (o >> 4) & 7;
    const int kk  = (c16 ^ (col & 7)) << 3;
    __builtin_amdgcn_global_load_lds(
        (const __attribute__((address_space(1))) void*)
            (Bt + (size_t)(col0 + col) * H_ + k0 + kk),
        (__attribute__((address_space(3))) void*)(lds + buf * 65536 + 32768 + o),
        16, 0, 0);
  };

  f32x4 acc[8][4];
  #pragma unroll
  for (int m = 0; m < 8; ++m)
    #pragma unroll
    for (int n = 0; n < 4; ++n) acc[m][n] = f32x4{0.f, 0.f, 0.f, 0.f};

  stageA(0, 0);
  #pragma unroll
  for (int r = 0; r < 4; ++r) stageB_round(0, 0, r);
  #pragma unroll
  for (int r = 0; r < 4; ++r) stageB_round(1, 1, r);
  asm volatile("s_waitcnt vmcnt(4)" ::: "memory");
  __builtin_amdgcn_sched_barrier(0);
  __builtin_amdgcn_s_barrier();

  for (int q = 0; q < NT; ++q) {
    const int cur = q & 1;
    const unsigned char* bufp = lds + cur * 65536;

    if (q + 1 < NT) stageA(q + 1, cur ^ 1);

    short8 bfr[4][2];
    #pragma unroll
    for (int n = 0; n < 4; ++n) {
      const int col = wc * 64 + n * 16 + cl;
      #pragma unroll
      for (int ks = 0; ks < 2; ++ks)
        bfr[n][ks] = *(const short8*)(bufp + 32768 + col * 128 +
                                      ((((ks << 2) + kgrp) ^ (col & 7)) << 4));
    }
    asm volatile("s_waitcnt lgkmcnt(0)" ::: "memory");
    __builtin_amdgcn_sched_barrier(0);
    __builtin_amdgcn_s_barrier();

    __builtin_amdgcn_s_setprio(1);
    #pragma unroll
    for (int g = 0; g < 4; ++g) {
      if (q + 2 < NT) stageB_round(q + 2, cur, g);
      short8 af[2][2];
      #pragma unroll
      for (int mm = 0; mm < 2; ++mm) {
        const int row = wr * 128 + (g * 2 + mm) * 16 + cl;
        #pragma unroll
        for (int ks = 0; ks < 2; ++ks)
          af[mm][ks] = *(const short8*)(bufp + row * 128 +
                                        ((((ks << 2) + kgrp) ^ (row & 7)) << 4));
      }
      #pragma unroll
      for (int ks = 0; ks < 2; ++ks)
        #pragma unroll
        for (int mm = 0; mm < 2; ++mm)
          #pragma unroll
          for (int n = 0; n < 4; ++n)
            acc[g * 2 + mm][n] = __builtin_amdgcn_mfma_f32_16x16x32_bf16(
                af[mm][ks], bfr[n][ks], acc[g * 2 + mm][n], 0, 0, 0);
    }
    __builtin_amdgcn_s_setprio(0);

    if (q + 2 < NT) {
      asm volatile("s_waitcnt vmcnt(4)" ::: "memory");
    } else if (q + 1 < NT) {
      asm volatile("s_waitcnt vmcnt(0)" ::: "memory");
    }
    __builtin_amdgcn_sched_barrier(0);
    __builtin_amdgcn_s_barrier();
  }

  #pragma unroll
  for (int m = 0; m < 8; ++m) {
    #pragma unroll
    for (int n = 0; n < 4; ++n) {
      const int gc = col0 + wc * 64 + n * 16 + cl;
      #pragma unroll
      for (int e2 = 0; e2 < 4; ++e2) {
        const int gr = row0 + wr * 128 + m * 16 + rg + e2;
        Cb[(size_t)gr * H_ + gc] = f2bf(acc[m][n][e2]);
      }
    }
  }

  #pragma unroll
  for (int c = 0; c < 2; ++c) {
    const int chunk = ((row0 + wr * 128) >> 6) + c;
    #pragma unroll
    for (int n = 0; n < 4; ++n) {
      const int h = col0 + wc * 64 + n * 16 + cl;
      const float a16 = powa[15 * H_ + h];
      float ep = 0.f;
      #pragma unroll
      for (int e2 = 0; e2 < 4; ++e2) {
        const int k = 15 - rg - e2;
        const float wk = (k == 0) ? 1.f : powa[(size_t)(k - 1) * H_ + h];
        float hsum = acc[c * 4 + 0][n][e2];
        hsum = fmaf(hsum, a16, acc[c * 4 + 1][n][e2]);
        hsum = fmaf(hsum, a16, acc[c * 4 + 2][n][e2]);
        hsum = fmaf(hsum, a16, acc[c * 4 + 3][n][e2]);
        ep = fmaf(wk, hsum, ep);
      }
      ep += __shfl_xor(ep, 16);
      ep += __shfl_xor(ep, 32);
      if (kgrp == 0)
        e[(size_t)chunk * H_ + h] = ep;
    }
  }
}

// ---------------------------------------------------------------------------
// Fused carry + scan + out-projection (kernel 3 of 3). One block per chunk.
// Inline carry: batched-8 predicated Horner over predecessors' e (L2-hot,
// loads independent -> one latency). Then scan -> swizzled LDS -> MFMA.
// ---------------------------------------------------------------------------
__global__ __launch_bounds__(256) void scan_out(
    const unsigned int* __restrict__ v, const float* __restrict__ e,
    const float* __restrict__ aarr, const unsigned short* __restrict__ Wo,
    const float* __restrict__ b_out, float* __restrict__ y)
{
  __shared__ __align__(16) unsigned char sbytes[64 * 1024];
  const int blk = blockIdx.x;
  const int b = blk >> 5, c = blk & 31;
  const int tid = threadIdx.x;
  const int lane = tid & 63, w = tid >> 6;
  const int row_base = blk * L_;

  {
    const int h0 = tid * 2;
    const float a0 = aarr[h0], a1 = aarr[h0 + 1];
    float aL0 = a0 * a0, aL1 = a1 * a1;
    aL0 *= aL0; aL1 *= aL1;
    aL0 *= aL0; aL1 *= aL1;
    aL0 *= aL0; aL1 *= aL1;
    aL0 *= aL0; aL1 *= aL1;
    aL0 *= aL0; aL1 *= aL1;                       // a^64
    float s0 = 0.f, s1 = 0.f;
    #pragma unroll
    for (int g = 0; g < 4; ++g) {
      float ev0[8], ev1[8];
      #pragma unroll
      for (int k = 0; k < 8; ++k) {
        const size_t o = ((size_t)(b * C_ + g * 8 + k)) * H_ + h0;
        ev0[k] = e[o]; ev1[k] = e[o + 1];
      }
      #pragma unroll
      for (int k = 0; k < 8; ++k) {
        const bool pred = (g * 8 + k) < c;
        s0 = pred ? fmaf(aL0, s0, ev0[k]) : s0;
        s1 = pred ? fmaf(aL1, s1, ev1[k]) : s1;
      }
    }
    const unsigned int* vp = v + (size_t)row_base * (H_ / 2) + tid;
    #pragma unroll 8
    for (int t = 0; t < L_; ++t) {
      const unsigned int pv = vp[(size_t)t * (H_ / 2)];
      s0 = fmaf(a0, s0, bf2f((unsigned short)(pv & 0xffff)));
      s1 = fmaf(a1, s1, bf2f((unsigned short)(pv >> 16)));
      const int byte = t * 1024 + ((tid * 4) ^ ((t & 7) << 4));
      *(unsigned int*)(sbytes + byte) =
          (unsigned int)f2bf(s0) | ((unsigned int)f2bf(s1) << 16);
    }
  }
  __syncthreads();

  f32x4 acc[4];
  #pragma unroll
  for (int n = 0; n < 4; ++n) acc[n] = f32x4{0.f, 0.f, 0.f, 0.f};
  const int r = w * 16 + (lane & 15);
  const int kof = (lane >> 4) * 8;
  #pragma unroll 4
  for (int k0 = 0; k0 < H_; k0 += 32) {
    const int byte = r * 1024 + (((k0 + kof) * 2) ^ ((r & 7) << 4));
    const short8 af = *(const short8*)(sbytes + byte);
    #pragma unroll
    for (int n = 0; n < 4; ++n) {
      const short8 bf = *(const short8*)(Wo + (size_t)(n * 16 + (lane & 15)) * H_ + k0 + kof);
      acc[n] = __builtin_amdgcn_mfma_f32_16x16x32_bf16(af, bf, acc[n], 0, 0, 0);
    }
  }
  const int cl = lane & 15, rg = (lane >> 4) * 4;
  #pragma unroll
  for (int n = 0; n < 4; ++n) {
    #pragma unroll
    for (int e2 = 0; e2 < 4; ++e2) {
      const int gr = row_base + w * 16 + rg + e2;
      const int gc = n * 16 + cl;
      y[(size_t)gr * O_ + gc] = acc[n][e2] + b_out[gc];
    }
  }
}

// ---------------------------------------------------------------------------
extern "C" void kernel_launch(void* const* d_in, const int* in_sizes, int n_in,
                              void* d_out, int out_size, void* d_ws, size_t ws_size,
                              hipStream_t stream)
{
  const float* obs   = (const float*)d_in[0];
  const float* act   = (const float*)d_in[1];
  const float* W_e   = (const float*)d_in[2];
  const float* b_e   = (const float*)d_in[3];
  const float* a_raw = (const float*)d_in[4];
  const float* W_B   = (const float*)d_in[5];
  const float* W_out = (const float*)d_in[6];
  const float* b_out = (const float*)d_in[7];
  float* y = (float*)d_out;

  char* w = (char*)d_ws;
  auto carve = [&](size_t bytes) {
    char* p = w; w += (bytes + 255) & ~(size_t)255; return p;
  };
  unsigned short* WBb   = (unsigned short*)carve((size_t)H_ * H_ * 2);
  unsigned short* Woutb = (unsigned short*)carve((size_t)O_ * H_ * 2);
  float*          aarr  = (float*)carve((size_t)H_ * 4);
  float*          powa  = (float*)carve((size_t)16 * H_ * 4);
  unsigned short* u     = (unsigned short*)carve((size_t)BT_ * H_ * 2);    // 33.5 MB
  unsigned short* v     = (unsigned short*)carve((size_t)BT_ * H_ * 2);    // 33.5 MB
  float*          e     = (float*)carve((size_t)NCHUNK * H_ * 4);          // 1 MB

  // 1) embed (+ inline weight prep) -> u
  embed_gemm<<<256, 512, 0, stream>>>(obs, act, W_e, b_e, a_raw, W_B, W_out,
                                      WBb, Woutb, aarr, powa, u);
  // 2) v = u @ WB^T (counted-vmcnt pipeline); epilogue emits e
  gemm_bproj<<<256, 512, 0, stream>>>(u, WBb, v, powa, e);
  // 3) fused carry + scan + out-projection -> y
  scan_out<<<NCHUNK, 256, 0, stream>>>((const unsigned int*)v, e, aarr,
                                       Woutb, b_out, y);
}